// Round 1
// baseline (580.519 us; speedup 1.0000x reference)
//
#include <hip/hip_runtime.h>

// GCN forward: 3x (GCNConv improved + ReLU) + GCNConv(out, 1 feature)
// N=50000 nodes, E=1.6M edges, H=64 features. All f32.

#define NN 50000
#define HF 64

// ---------------- CSR build ----------------

__global__ void k_zero_i32(int* p, int n) {
    int i = blockIdx.x * blockDim.x + threadIdx.x;
    if (i < n) p[i] = 0;
}

__global__ void k_deg(const int* __restrict__ dst, int* __restrict__ deg, int e) {
    int i = blockIdx.x * blockDim.x + threadIdx.x;
    if (i < e) atomicAdd(&deg[dst[i]], 1);
}

__global__ void k_dis(const int* __restrict__ deg, float* __restrict__ di,
                      float* __restrict__ dp, int n) {
    int i = blockIdx.x * blockDim.x + threadIdx.x;
    if (i < n) {
        float d = (float)deg[i];
        di[i] = rsqrtf(d + 2.0f);   // improved=True: self-loop weight 2
        dp[i] = rsqrtf(d + 1.0f);   // output layer: improved=False
    }
}

// single-block exclusive scan of deg -> offs (and cursor copy)
__global__ void k_scan(const int* __restrict__ deg, int* __restrict__ offs,
                       int* __restrict__ cursor, int n, int total) {
    __shared__ int sd[1024];
    int tid = threadIdx.x;
    int chunk = (n + 1023) >> 10;
    int beg = tid * chunk;
    int end = beg + chunk; if (end > n) end = n; if (beg > n) beg = n;
    int s = 0;
    for (int i = beg; i < end; ++i) s += deg[i];
    sd[tid] = s;
    __syncthreads();
    for (int o = 1; o < 1024; o <<= 1) {
        int v = (tid >= o) ? sd[tid - o] : 0;
        __syncthreads();
        sd[tid] += v;
        __syncthreads();
    }
    int run = sd[tid] - s;   // exclusive prefix
    for (int i = beg; i < end; ++i) {
        offs[i] = run; cursor[i] = run;
        run += deg[i];
    }
    if (tid == 1023) offs[n] = total;
}

__global__ void k_fill(const int* __restrict__ src, const int* __restrict__ dst,
                       const float* __restrict__ di, int* __restrict__ cursor,
                       int* __restrict__ csrs, float* __restrict__ csrw, int e) {
    int i = blockIdx.x * blockDim.x + threadIdx.x;
    if (i < e) {
        int s = src[i], t = dst[i];
        int pos = atomicAdd(&cursor[t], 1);
        csrs[pos] = s;
        csrw[pos] = di[s] * di[t];   // improved-norm, reused by 3 layers
    }
}

// ---------------- dense GEMM: C[n,64] = A[n,64] @ W[64,64] ----------------
// 256 threads, tile = 128 nodes x 64 features, K=64 in one shot.
// per-thread 4 nodes x 8 features.

#define GM_BN 128
__global__ __launch_bounds__(256) void k_gemm(const float* __restrict__ A,
                                              const float* __restrict__ W,
                                              float* __restrict__ C, int n) {
    __shared__ float xT[64][132];   // [k][node], +4 pad keeps rows 16B-aligned
    __shared__ float Wl[64][64];    // [k][f]
    int tid = threadIdx.x;
    int nb = blockIdx.x * GM_BN;

    // load W (64x64): 1024 float4, 4 per thread, linear -> coalesced
    for (int r = 0; r < 4; ++r) {
        int q = tid + 256 * r;
        int row = q >> 4, c4 = (q & 15) << 2;
        *(float4*)&Wl[row][c4] = *(const float4*)&W[row * 64 + c4];
    }
    // load x tile transposed: 128x64 floats = 2048 float4, 8 per thread
    for (int r = 0; r < 8; ++r) {
        int q = tid + 256 * r;
        int nl = q >> 4, k0 = (q & 15) << 2;
        float4 v = make_float4(0.f, 0.f, 0.f, 0.f);
        if (nb + nl < n) v = *(const float4*)&A[(size_t)(nb + nl) * HF + k0];
        xT[k0 + 0][nl] = v.x; xT[k0 + 1][nl] = v.y;
        xT[k0 + 2][nl] = v.z; xT[k0 + 3][nl] = v.w;
    }
    __syncthreads();

    int tx = tid & 7;          // f0 = tx*8
    int ty = tid >> 3;         // n0 = ty*4
    int f0 = tx * 8, n0 = ty * 4;
    float acc[4][8];
#pragma unroll
    for (int i = 0; i < 4; ++i)
#pragma unroll
        for (int j = 0; j < 8; ++j) acc[i][j] = 0.f;

#pragma unroll 4
    for (int k = 0; k < 64; ++k) {
        float4 xa = *(float4*)&xT[k][n0];
        float4 wa = *(float4*)&Wl[k][f0];
        float4 wb = *(float4*)&Wl[k][f0 + 4];
        float xs[4] = {xa.x, xa.y, xa.z, xa.w};
        float wsv[8] = {wa.x, wa.y, wa.z, wa.w, wb.x, wb.y, wb.z, wb.w};
#pragma unroll
        for (int i = 0; i < 4; ++i)
#pragma unroll
            for (int j = 0; j < 8; ++j) acc[i][j] += xs[i] * wsv[j];
    }

#pragma unroll
    for (int i = 0; i < 4; ++i) {
        int nn = nb + n0 + i;
        if (nn < n) {
            *(float4*)&C[(size_t)nn * HF + f0] =
                make_float4(acc[i][0], acc[i][1], acc[i][2], acc[i][3]);
            *(float4*)&C[(size_t)nn * HF + f0 + 4] =
                make_float4(acc[i][4], acc[i][5], acc[i][6], acc[i][7]);
        }
    }
}

// ---------------- sparse aggregation: one wave per node, lane=feature ----------------
// out[n,f] = relu?( sum_e w[e]*P[src[e],f] + fill*dis[n]^2*P[n,f] + bias[f] )

__global__ void k_agg(const float* __restrict__ P, const int* __restrict__ offs,
                      const int* __restrict__ csrs, const float* __restrict__ csrw,
                      const float* __restrict__ dis, const float* __restrict__ bias,
                      float* __restrict__ out, int n, int do_relu, float fill) {
    int wid = (blockIdx.x * blockDim.x + threadIdx.x) >> 6;
    int f = threadIdx.x & 63;
    if (wid >= n) return;
    int beg = offs[wid], end = offs[wid + 1];
    float acc = 0.f;
    int e = beg;
    int end4 = beg + ((end - beg) & ~3);
    for (; e < end4; e += 4) {
        int s0 = csrs[e + 0], s1 = csrs[e + 1], s2 = csrs[e + 2], s3 = csrs[e + 3];
        float w0 = csrw[e + 0], w1 = csrw[e + 1], w2 = csrw[e + 2], w3 = csrw[e + 3];
        float p0 = P[(size_t)s0 * HF + f];
        float p1 = P[(size_t)s1 * HF + f];
        float p2 = P[(size_t)s2 * HF + f];
        float p3 = P[(size_t)s3 * HF + f];
        acc += w0 * p0; acc += w1 * p1; acc += w2 * p2; acc += w3 * p3;
    }
    for (; e < end; ++e) acc += csrw[e] * P[(size_t)csrs[e] * HF + f];
    float dn = dis[wid];
    acc += fill * dn * dn * P[(size_t)wid * HF + f];
    acc += bias[f];
    if (do_relu) acc = fmaxf(acc, 0.f);
    out[(size_t)wid * HF + f] = acc;
}

// ---------------- output projection: z2[n] = dis_p[n] * (h[n,:]·W_out) ----------------

__global__ void k_z(const float* __restrict__ H, const float* __restrict__ Wout,
                    const float* __restrict__ dp, float* __restrict__ z2, int n) {
    int wid = (blockIdx.x * blockDim.x + threadIdx.x) >> 6;
    int f = threadIdx.x & 63;
    if (wid >= n) return;
    float v = H[(size_t)wid * HF + f] * Wout[f];
#pragma unroll
    for (int o = 32; o > 0; o >>= 1) v += __shfl_down(v, o, 64);
    if (f == 0) z2[wid] = v * dp[wid];
}

// out[n] = dis_p[n] * (sum_e z2[src] + z2[n]) + b_out
__global__ void k_out(const float* __restrict__ z2, const int* __restrict__ offs,
                      const int* __restrict__ csrs, const float* __restrict__ dp,
                      const float* __restrict__ bout, float* __restrict__ out, int n) {
    int i = blockIdx.x * blockDim.x + threadIdx.x;
    if (i >= n) return;
    int beg = offs[i], end = offs[i + 1];
    float acc = 0.f;
    for (int e = beg; e < end; ++e) acc += z2[csrs[e]];
    out[i] = dp[i] * (acc + z2[i]) + bout[0];
}

extern "C" void kernel_launch(void* const* d_in, const int* in_sizes, int n_in,
                              void* d_out, int out_size, void* d_ws, size_t ws_size,
                              hipStream_t stream) {
    const float* x    = (const float*)d_in[0];
    const int*   ei   = (const int*)d_in[1];
    const float* W_in = (const float*)d_in[2];
    const float* b_in = (const float*)d_in[3];
    const float* W_h1 = (const float*)d_in[4];
    const float* b_h1 = (const float*)d_in[5];
    const float* W_h2 = (const float*)d_in[6];
    const float* b_h2 = (const float*)d_in[7];
    const float* W_out= (const float*)d_in[8];
    const float* b_out= (const float*)d_in[9];
    float* out = (float*)d_out;

    const int n = in_sizes[0] / HF;        // 50000
    const int E = in_sizes[1] / 2;         // 1.6M
    const int* src = ei;
    const int* dst = ei + E;

    // workspace layout (256B aligned slabs)
    char* ws = (char*)d_ws;
    size_t o = 0;
    auto alloc = [&](size_t bytes) -> void* {
        void* p = ws + o;
        o += (bytes + 255) & ~(size_t)255;
        return p;
    };
    int*   deg    = (int*)  alloc((size_t)n * 4);
    int*   offs   = (int*)  alloc((size_t)(n + 1) * 4);
    int*   cursor = (int*)  alloc((size_t)n * 4);
    float* di     = (float*)alloc((size_t)n * 4);
    float* dp     = (float*)alloc((size_t)n * 4);
    int*   csrs   = (int*)  alloc((size_t)E * 4);
    float* csrw   = (float*)alloc((size_t)E * 4);
    float* hW     = (float*)alloc((size_t)n * HF * 4);
    float* hA     = (float*)alloc((size_t)n * HF * 4);
    float* hB     = (float*)alloc((size_t)n * HF * 4);
    float* z2     = (float*)alloc((size_t)n * 4);

    const int TB = 256;
    int gbN  = (n + TB - 1) / TB;          // node-parallel grids
    int gbE  = (E + TB - 1) / TB;          // edge-parallel grids
    int gbW  = (n * 64 + TB - 1) / TB;     // wave-per-node grids (4 waves/block)
    int gbG  = (n + GM_BN - 1) / GM_BN;    // gemm grid

    // ---- CSR build ----
    k_zero_i32<<<gbN, TB, 0, stream>>>(deg, n);
    k_deg<<<gbE, TB, 0, stream>>>(dst, deg, E);
    k_dis<<<gbN, TB, 0, stream>>>(deg, di, dp, n);
    k_scan<<<1, 1024, 0, stream>>>(deg, offs, cursor, n, E);
    k_fill<<<gbE, TB, 0, stream>>>(src, dst, di, cursor, csrs, csrw, E);

    // ---- layer 1 ----
    k_gemm<<<gbG, TB, 0, stream>>>(x, W_in, hW, n);
    k_agg<<<gbW, TB, 0, stream>>>(hW, offs, csrs, csrw, di, b_in, hA, n, 1, 2.0f);
    // ---- layer 2 ----
    k_gemm<<<gbG, TB, 0, stream>>>(hA, W_h1, hW, n);
    k_agg<<<gbW, TB, 0, stream>>>(hW, offs, csrs, csrw, di, b_h1, hB, n, 1, 2.0f);
    // ---- layer 3 ----
    k_gemm<<<gbG, TB, 0, stream>>>(hB, W_h2, hW, n);
    k_agg<<<gbW, TB, 0, stream>>>(hW, offs, csrs, csrw, di, b_h2, hA, n, 1, 2.0f);
    // ---- output layer (project to 1 feature first, then aggregate) ----
    k_z<<<gbW, TB, 0, stream>>>(hA, W_out, dp, z2, n);
    k_out<<<gbN, TB, 0, stream>>>(z2, offs, csrs, dp, b_out, out, n);
}

// Round 2
// 544.969 us; speedup vs baseline: 1.0652x; 1.0652x over previous
//
#include <hip/hip_runtime.h>

// GCN forward: 3x (GCNConv improved + ReLU) + GCNConv(out, 1 feature)
// N=50000 nodes, E=1.6M edges, H=64 features. All f32.
// CSR src stored as ushort (N < 65536) so the scatter target is L2-resident.

#define NN 50000
#define HF 64

// ---------------- CSR build ----------------

__global__ void k_zero_i32(int* p, int n) {
    int i = blockIdx.x * blockDim.x + threadIdx.x;
    if (i < n) p[i] = 0;
}

__global__ void k_deg(const int* __restrict__ dst, int* __restrict__ deg, int e) {
    int i = blockIdx.x * blockDim.x + threadIdx.x;
    if (i < e) atomicAdd(&deg[dst[i]], 1);
}

__global__ void k_dis(const int* __restrict__ deg, float* __restrict__ di,
                      float* __restrict__ dp, int n) {
    int i = blockIdx.x * blockDim.x + threadIdx.x;
    if (i < n) {
        float d = (float)deg[i];
        di[i] = rsqrtf(d + 2.0f);   // improved=True: self-loop weight 2
        dp[i] = rsqrtf(d + 1.0f);   // output layer: improved=False
    }
}

// single-block exclusive scan of deg -> offs (and cursor copy)
__global__ void k_scan(const int* __restrict__ deg, int* __restrict__ offs,
                       int* __restrict__ cursor, int n, int total) {
    __shared__ int sd[1024];
    int tid = threadIdx.x;
    int chunk = (n + 1023) >> 10;
    int beg = tid * chunk;
    int end = beg + chunk; if (end > n) end = n; if (beg > n) beg = n;
    int s = 0;
    for (int i = beg; i < end; ++i) s += deg[i];
    sd[tid] = s;
    __syncthreads();
    for (int o = 1; o < 1024; o <<= 1) {
        int v = (tid >= o) ? sd[tid - o] : 0;
        __syncthreads();
        sd[tid] += v;
        __syncthreads();
    }
    int run = sd[tid] - s;   // exclusive prefix
    for (int i = beg; i < end; ++i) {
        offs[i] = run; cursor[i] = run;
        run += deg[i];
    }
    if (tid == 1023) offs[n] = total;
}

// pure 2B scatter; csrs (3.2 MB) fits in each XCD's 4 MB L2
__global__ void k_fill(const int* __restrict__ src, const int* __restrict__ dst,
                       int* __restrict__ cursor, ushort* __restrict__ csrs, int e) {
    int i = blockIdx.x * blockDim.x + threadIdx.x;
    if (i < e) {
        int s = src[i], t = dst[i];
        int pos = atomicAdd(&cursor[t], 1);
        csrs[pos] = (ushort)s;
    }
}

// ---------------- dense GEMM: C[n,64] = A[n,64] @ W[64,64] ----------------
// 256 threads, tile = 128 nodes x 64 features, K=64 in one shot.
// per-thread 4 nodes x 8 features.

#define GM_BN 128
__global__ __launch_bounds__(256) void k_gemm(const float* __restrict__ A,
                                              const float* __restrict__ W,
                                              float* __restrict__ C, int n) {
    __shared__ float xT[64][132];   // [k][node], +4 pad keeps rows 16B-aligned
    __shared__ float Wl[64][64];    // [k][f]
    int tid = threadIdx.x;
    int nb = blockIdx.x * GM_BN;

    for (int r = 0; r < 4; ++r) {
        int q = tid + 256 * r;
        int row = q >> 4, c4 = (q & 15) << 2;
        *(float4*)&Wl[row][c4] = *(const float4*)&W[row * 64 + c4];
    }
    for (int r = 0; r < 8; ++r) {
        int q = tid + 256 * r;
        int nl = q >> 4, k0 = (q & 15) << 2;
        float4 v = make_float4(0.f, 0.f, 0.f, 0.f);
        if (nb + nl < n) v = *(const float4*)&A[(size_t)(nb + nl) * HF + k0];
        xT[k0 + 0][nl] = v.x; xT[k0 + 1][nl] = v.y;
        xT[k0 + 2][nl] = v.z; xT[k0 + 3][nl] = v.w;
    }
    __syncthreads();

    int tx = tid & 7;
    int ty = tid >> 3;
    int f0 = tx * 8, n0 = ty * 4;
    float acc[4][8];
#pragma unroll
    for (int i = 0; i < 4; ++i)
#pragma unroll
        for (int j = 0; j < 8; ++j) acc[i][j] = 0.f;

#pragma unroll 4
    for (int k = 0; k < 64; ++k) {
        float4 xa = *(float4*)&xT[k][n0];
        float4 wa = *(float4*)&Wl[k][f0];
        float4 wb = *(float4*)&Wl[k][f0 + 4];
        float xs[4] = {xa.x, xa.y, xa.z, xa.w};
        float wsv[8] = {wa.x, wa.y, wa.z, wa.w, wb.x, wb.y, wb.z, wb.w};
#pragma unroll
        for (int i = 0; i < 4; ++i)
#pragma unroll
            for (int j = 0; j < 8; ++j) acc[i][j] += xs[i] * wsv[j];
    }

#pragma unroll
    for (int i = 0; i < 4; ++i) {
        int nn = nb + n0 + i;
        if (nn < n) {
            *(float4*)&C[(size_t)nn * HF + f0] =
                make_float4(acc[i][0], acc[i][1], acc[i][2], acc[i][3]);
            *(float4*)&C[(size_t)nn * HF + f0 + 4] =
                make_float4(acc[i][4], acc[i][5], acc[i][6], acc[i][7]);
        }
    }
}

// ---------------- sparse aggregation: one wave per node, lane=feature ----------------
// out[n,f] = relu?( sum_e di[s]*di[n]*P[s,f] + fill*di[n]^2*P[n,f] + bias[f] )

__global__ void k_agg(const float* __restrict__ P, const int* __restrict__ offs,
                      const ushort* __restrict__ csrs, const float* __restrict__ di,
                      const float* __restrict__ bias, float* __restrict__ out,
                      int n, int do_relu, float fill) {
    int wid = (blockIdx.x * blockDim.x + threadIdx.x) >> 6;
    int f = threadIdx.x & 63;
    if (wid >= n) return;
    int beg = offs[wid], end = offs[wid + 1];
    float dw = di[wid];                 // wave-uniform
    float acc = 0.f;
    int e = beg;
    int end4 = beg + ((end - beg) & ~3);
    for (; e < end4; e += 4) {
        int s0 = csrs[e + 0], s1 = csrs[e + 1], s2 = csrs[e + 2], s3 = csrs[e + 3];
        float w0 = di[s0], w1 = di[s1], w2 = di[s2], w3 = di[s3];  // broadcast loads
        float p0 = P[(size_t)s0 * HF + f];
        float p1 = P[(size_t)s1 * HF + f];
        float p2 = P[(size_t)s2 * HF + f];
        float p3 = P[(size_t)s3 * HF + f];
        acc += w0 * p0; acc += w1 * p1; acc += w2 * p2; acc += w3 * p3;
    }
    for (; e < end; ++e) {
        int s = csrs[e];
        acc += di[s] * P[(size_t)s * HF + f];
    }
    acc *= dw;                          // fold di[dst] once
    acc += fill * dw * dw * P[(size_t)wid * HF + f];
    acc += bias[f];
    if (do_relu) acc = fmaxf(acc, 0.f);
    out[(size_t)wid * HF + f] = acc;
}

// ---------------- output projection: z2[n] = dis_p[n] * (h[n,:]·W_out) ----------------

__global__ void k_z(const float* __restrict__ H, const float* __restrict__ Wout,
                    const float* __restrict__ dp, float* __restrict__ z2, int n) {
    int wid = (blockIdx.x * blockDim.x + threadIdx.x) >> 6;
    int f = threadIdx.x & 63;
    if (wid >= n) return;
    float v = H[(size_t)wid * HF + f] * Wout[f];
#pragma unroll
    for (int o = 32; o > 0; o >>= 1) v += __shfl_down(v, o, 64);
    if (f == 0) z2[wid] = v * dp[wid];
}

// out[n] = dis_p[n] * (sum_e z2[src] + z2[n]) + b_out
__global__ void k_out(const float* __restrict__ z2, const int* __restrict__ offs,
                      const ushort* __restrict__ csrs, const float* __restrict__ dp,
                      const float* __restrict__ bout, float* __restrict__ out, int n) {
    int i = blockIdx.x * blockDim.x + threadIdx.x;
    if (i >= n) return;
    int beg = offs[i], end = offs[i + 1];
    float acc = 0.f;
    for (int e = beg; e < end; ++e) acc += z2[csrs[e]];
    out[i] = dp[i] * (acc + z2[i]) + bout[0];
}

extern "C" void kernel_launch(void* const* d_in, const int* in_sizes, int n_in,
                              void* d_out, int out_size, void* d_ws, size_t ws_size,
                              hipStream_t stream) {
    const float* x    = (const float*)d_in[0];
    const int*   ei   = (const int*)d_in[1];
    const float* W_in = (const float*)d_in[2];
    const float* b_in = (const float*)d_in[3];
    const float* W_h1 = (const float*)d_in[4];
    const float* b_h1 = (const float*)d_in[5];
    const float* W_h2 = (const float*)d_in[6];
    const float* b_h2 = (const float*)d_in[7];
    const float* W_out= (const float*)d_in[8];
    const float* b_out= (const float*)d_in[9];
    float* out = (float*)d_out;

    const int n = in_sizes[0] / HF;        // 50000  (must be < 65536 for ushort CSR)
    const int E = in_sizes[1] / 2;         // 1.6M
    const int* src = ei;
    const int* dst = ei + E;

    char* ws = (char*)d_ws;
    size_t o = 0;
    auto alloc = [&](size_t bytes) -> void* {
        void* p = ws + o;
        o += (bytes + 255) & ~(size_t)255;
        return p;
    };
    int*    deg    = (int*)   alloc((size_t)n * 4);
    int*    offs   = (int*)   alloc((size_t)(n + 1) * 4);
    int*    cursor = (int*)   alloc((size_t)n * 4);
    float*  di     = (float*) alloc((size_t)n * 4);
    float*  dp     = (float*) alloc((size_t)n * 4);
    ushort* csrs   = (ushort*)alloc((size_t)E * 2);
    float*  hW     = (float*) alloc((size_t)n * HF * 4);
    float*  hA     = (float*) alloc((size_t)n * HF * 4);
    float*  hB     = (float*) alloc((size_t)n * HF * 4);
    float*  z2     = (float*) alloc((size_t)n * 4);

    const int TB = 256;
    int gbN  = (n + TB - 1) / TB;
    int gbE  = (E + TB - 1) / TB;
    int gbW  = (n * 64 + TB - 1) / TB;
    int gbG  = (n + GM_BN - 1) / GM_BN;

    // ---- CSR build ----
    k_zero_i32<<<gbN, TB, 0, stream>>>(deg, n);
    k_deg<<<gbE, TB, 0, stream>>>(dst, deg, E);
    k_dis<<<gbN, TB, 0, stream>>>(deg, di, dp, n);
    k_scan<<<1, 1024, 0, stream>>>(deg, offs, cursor, n, E);
    k_fill<<<gbE, TB, 0, stream>>>(src, dst, cursor, csrs, E);

    // ---- layer 1 ----
    k_gemm<<<gbG, TB, 0, stream>>>(x, W_in, hW, n);
    k_agg<<<gbW, TB, 0, stream>>>(hW, offs, csrs, di, b_in, hA, n, 1, 2.0f);
    // ---- layer 2 ----
    k_gemm<<<gbG, TB, 0, stream>>>(hA, W_h1, hW, n);
    k_agg<<<gbW, TB, 0, stream>>>(hW, offs, csrs, di, b_h1, hB, n, 1, 2.0f);
    // ---- layer 3 ----
    k_gemm<<<gbG, TB, 0, stream>>>(hB, W_h2, hW, n);
    k_agg<<<gbW, TB, 0, stream>>>(hW, offs, csrs, di, b_h2, hA, n, 1, 2.0f);
    // ---- output layer ----
    k_z<<<gbW, TB, 0, stream>>>(hA, W_out, dp, z2, n);
    k_out<<<gbN, TB, 0, stream>>>(z2, offs, csrs, dp, b_out, out, n);
}

// Round 3
// 494.878 us; speedup vs baseline: 1.1731x; 1.1012x over previous
//
#include <hip/hip_runtime.h>

// GCN forward: 3x (GCNConv improved + ReLU) + GCNConv(out, 1 feature)
// N=50000 nodes, E=1.6M edges, H=64 features. All f32.
// CSR built via atomic-free MSD counting sort (global atomics cost ~64B
// memory-side traffic each on gfx950 -> ~230us for 3.2M atomics; LDS-only
// atomics avoid that entirely).

#define HF 64
#define EPB 4096          // edges per block in passes A/B

// ---------------- pass A: coarse histogram (bucket = dst>>8) ----------------
__global__ __launch_bounds__(256) void pA_hist(const int* __restrict__ dst,
                                               int* __restrict__ histA, int E) {
    __shared__ int h[256];
    int g = blockIdx.x, t = threadIdx.x;
    h[t] = 0;
    __syncthreads();
    int beg = g * EPB, end = min(beg + EPB, E);
    for (int i = beg + t; i < end; i += 256) atomicAdd(&h[dst[i] >> 8], 1);
    __syncthreads();
    histA[g * 256 + t] = h[t];
}

// ---------------- scan: bucket-major exclusive scan of hist table ----------------
// in-place: histA[g*256+b] becomes the exclusive position for (bucket b, block g).
// coarse[b] = start of bucket b in the sorted edge array; coarse[256] = E.
#define ST 1024
__global__ __launch_bounds__(ST) void pScan(int* __restrict__ hist,
                                            int* __restrict__ coarse, int G, int E) {
    __shared__ int sd[ST];
    int t = threadIdx.x;
    int M = 256 * G;
    int chunk = (M + ST - 1) / ST;
    int beg = t * chunk, end = min(beg + chunk, M);
    int s = 0, b = 0, g = 0;
    if (beg < M) { b = beg / G; g = beg - b * G; }
    for (int fi = beg; fi < end; ++fi) {
        s += hist[g * 256 + b];
        if (++g == G) { g = 0; ++b; }
    }
    sd[t] = s;
    __syncthreads();
    for (int o = 1; o < ST; o <<= 1) {
        int u = (t >= o) ? sd[t - o] : 0;
        __syncthreads();
        sd[t] += u;
        __syncthreads();
    }
    int run = sd[t] - s;   // exclusive prefix at beg
    if (beg < M) { b = beg / G; g = beg - b * G; }
    for (int fi = beg; fi < end; ++fi) {
        int idx = g * 256 + b;
        int v = hist[idx];
        hist[idx] = run;
        if (g == 0) coarse[b] = run;
        run += v;
        if (++g == G) { g = 0; ++b; }
    }
    if (t == ST - 1) coarse[256] = E;
}

// ---------------- pass B: coarse scatter (LDS cursors, no global atomics) ----------------
__global__ __launch_bounds__(256) void pB_scatter(const int* __restrict__ src,
                                                  const int* __restrict__ dst,
                                                  const int* __restrict__ posTable,
                                                  unsigned int* __restrict__ tmp, int E) {
    __shared__ int cur[256];
    int g = blockIdx.x, t = threadIdx.x;
    cur[t] = posTable[g * 256 + t];
    __syncthreads();
    int beg = g * EPB, end = min(beg + EPB, E);
    for (int i = beg + t; i < end; i += 256) {
        int d = dst[i], s = src[i];
        int pos = atomicAdd(&cur[d >> 8], 1);
        tmp[pos] = ((unsigned int)(d & 255) << 16) | (unsigned int)(s & 0xFFFF);
    }
}

// ---------------- pass C: per-bucket fine counting sort + CSR metadata ----------------
// bucket b covers dst in [b*256, b*256+256). Emits csrs (ushort src, dst-grouped),
// offs, di (improved norm), dp (plain norm).
__global__ __launch_bounds__(256) void pC_build(const unsigned int* __restrict__ tmp,
                                                const int* __restrict__ coarse,
                                                ushort* __restrict__ csrs,
                                                int* __restrict__ offs,
                                                float* __restrict__ di,
                                                float* __restrict__ dp,
                                                int n, int E, int NB) {
    __shared__ int hist[256];
    __shared__ int cur[256];
    __shared__ int scanbuf[256];
    int b = blockIdx.x, t = threadIdx.x;
    int beg = coarse[b], end = coarse[b + 1];
    hist[t] = 0;
    __syncthreads();
    for (int i = beg + t; i < end; i += 256) atomicAdd(&hist[tmp[i] >> 16], 1);
    __syncthreads();
    int v = hist[t];
    scanbuf[t] = v;
    __syncthreads();
    for (int o = 1; o < 256; o <<= 1) {
        int u = (t >= o) ? scanbuf[t - o] : 0;
        __syncthreads();
        scanbuf[t] += u;
        __syncthreads();
    }
    int excl = scanbuf[t] - v;
    cur[t] = beg + excl;
    int d = (b << 8) + t;
    if (d < n) {
        offs[d] = beg + excl;
        float df = (float)v;
        di[d] = rsqrtf(df + 2.0f);   // improved=True: self-loop weight 2
        dp[d] = rsqrtf(df + 1.0f);   // output layer: improved=False
    }
    if (b == NB - 1 && t == 0) offs[n] = E;
    __syncthreads();
    for (int i = beg + t; i < end; i += 256) {
        unsigned int e = tmp[i];
        int pos = atomicAdd(&cur[e >> 16], 1);
        csrs[pos] = (ushort)(e & 0xFFFFu);
    }
}

// ---------------- dense GEMM: C[n,64] = A[n,64] @ W[64,64] ----------------
#define GM_BN 128
__global__ __launch_bounds__(256) void k_gemm(const float* __restrict__ A,
                                              const float* __restrict__ W,
                                              float* __restrict__ C, int n) {
    __shared__ float xT[64][132];
    __shared__ float Wl[64][64];
    int tid = threadIdx.x;
    int nb = blockIdx.x * GM_BN;

    for (int r = 0; r < 4; ++r) {
        int q = tid + 256 * r;
        int row = q >> 4, c4 = (q & 15) << 2;
        *(float4*)&Wl[row][c4] = *(const float4*)&W[row * 64 + c4];
    }
    for (int r = 0; r < 8; ++r) {
        int q = tid + 256 * r;
        int nl = q >> 4, k0 = (q & 15) << 2;
        float4 v = make_float4(0.f, 0.f, 0.f, 0.f);
        if (nb + nl < n) v = *(const float4*)&A[(size_t)(nb + nl) * HF + k0];
        xT[k0 + 0][nl] = v.x; xT[k0 + 1][nl] = v.y;
        xT[k0 + 2][nl] = v.z; xT[k0 + 3][nl] = v.w;
    }
    __syncthreads();

    int tx = tid & 7;
    int ty = tid >> 3;
    int f0 = tx * 8, n0 = ty * 4;
    float acc[4][8];
#pragma unroll
    for (int i = 0; i < 4; ++i)
#pragma unroll
        for (int j = 0; j < 8; ++j) acc[i][j] = 0.f;

#pragma unroll 4
    for (int k = 0; k < 64; ++k) {
        float4 xa = *(float4*)&xT[k][n0];
        float4 wa = *(float4*)&Wl[k][f0];
        float4 wb = *(float4*)&Wl[k][f0 + 4];
        float xs[4] = {xa.x, xa.y, xa.z, xa.w};
        float wsv[8] = {wa.x, wa.y, wa.z, wa.w, wb.x, wb.y, wb.z, wb.w};
#pragma unroll
        for (int i = 0; i < 4; ++i)
#pragma unroll
            for (int j = 0; j < 8; ++j) acc[i][j] += xs[i] * wsv[j];
    }

#pragma unroll
    for (int i = 0; i < 4; ++i) {
        int nn = nb + n0 + i;
        if (nn < n) {
            *(float4*)&C[(size_t)nn * HF + f0] =
                make_float4(acc[i][0], acc[i][1], acc[i][2], acc[i][3]);
            *(float4*)&C[(size_t)nn * HF + f0 + 4] =
                make_float4(acc[i][4], acc[i][5], acc[i][6], acc[i][7]);
        }
    }
}

// ---------------- sparse aggregation: one wave per node, lane=feature ----------------
__global__ void k_agg(const float* __restrict__ P, const int* __restrict__ offs,
                      const ushort* __restrict__ csrs, const float* __restrict__ di,
                      const float* __restrict__ bias, float* __restrict__ out,
                      int n, int do_relu, float fill) {
    int wid = (blockIdx.x * blockDim.x + threadIdx.x) >> 6;
    int f = threadIdx.x & 63;
    if (wid >= n) return;
    int beg = offs[wid], end = offs[wid + 1];
    float dw = di[wid];
    float acc = 0.f;
    int e = beg;
    int end4 = beg + ((end - beg) & ~3);
    for (; e < end4; e += 4) {
        int s0 = csrs[e + 0], s1 = csrs[e + 1], s2 = csrs[e + 2], s3 = csrs[e + 3];
        float w0 = di[s0], w1 = di[s1], w2 = di[s2], w3 = di[s3];
        float p0 = P[(size_t)s0 * HF + f];
        float p1 = P[(size_t)s1 * HF + f];
        float p2 = P[(size_t)s2 * HF + f];
        float p3 = P[(size_t)s3 * HF + f];
        acc += w0 * p0; acc += w1 * p1; acc += w2 * p2; acc += w3 * p3;
    }
    for (; e < end; ++e) {
        int s = csrs[e];
        acc += di[s] * P[(size_t)s * HF + f];
    }
    acc *= dw;
    acc += fill * dw * dw * P[(size_t)wid * HF + f];
    acc += bias[f];
    if (do_relu) acc = fmaxf(acc, 0.f);
    out[(size_t)wid * HF + f] = acc;
}

// ---------------- output projection ----------------
__global__ void k_z(const float* __restrict__ H, const float* __restrict__ Wout,
                    const float* __restrict__ dp, float* __restrict__ z2, int n) {
    int wid = (blockIdx.x * blockDim.x + threadIdx.x) >> 6;
    int f = threadIdx.x & 63;
    if (wid >= n) return;
    float v = H[(size_t)wid * HF + f] * Wout[f];
#pragma unroll
    for (int o = 32; o > 0; o >>= 1) v += __shfl_down(v, o, 64);
    if (f == 0) z2[wid] = v * dp[wid];
}

__global__ void k_out(const float* __restrict__ z2, const int* __restrict__ offs,
                      const ushort* __restrict__ csrs, const float* __restrict__ dp,
                      const float* __restrict__ bout, float* __restrict__ out, int n) {
    int i = blockIdx.x * blockDim.x + threadIdx.x;
    if (i >= n) return;
    int beg = offs[i], end = offs[i + 1];
    float acc = 0.f;
    for (int e = beg; e < end; ++e) acc += z2[csrs[e]];
    out[i] = dp[i] * (acc + z2[i]) + bout[0];
}

extern "C" void kernel_launch(void* const* d_in, const int* in_sizes, int n_in,
                              void* d_out, int out_size, void* d_ws, size_t ws_size,
                              hipStream_t stream) {
    const float* x    = (const float*)d_in[0];
    const int*   ei   = (const int*)d_in[1];
    const float* W_in = (const float*)d_in[2];
    const float* b_in = (const float*)d_in[3];
    const float* W_h1 = (const float*)d_in[4];
    const float* b_h1 = (const float*)d_in[5];
    const float* W_h2 = (const float*)d_in[6];
    const float* b_h2 = (const float*)d_in[7];
    const float* W_out= (const float*)d_in[8];
    const float* b_out= (const float*)d_in[9];
    float* out = (float*)d_out;

    const int n = in_sizes[0] / HF;        // 50000 (< 65536: ushort CSR ok)
    const int E = in_sizes[1] / 2;         // 1.6M
    const int* src = ei;
    const int* dst = ei + E;

    const int G  = (E + EPB - 1) / EPB;    // blocks in passes A/B
    const int NB = (n + 255) >> 8;         // coarse buckets actually populated

    char* ws = (char*)d_ws;
    size_t o = 0;
    auto alloc = [&](size_t bytes) -> void* {
        void* p = ws + o;
        o += (bytes + 255) & ~(size_t)255;
        return p;
    };
    int*          offs   = (int*)   alloc((size_t)(n + 1) * 4);
    float*        di     = (float*) alloc((size_t)n * 4);
    float*        dp     = (float*) alloc((size_t)n * 4);
    ushort*       csrs   = (ushort*)alloc((size_t)E * 2);
    unsigned int* tmp    = (unsigned int*)alloc((size_t)E * 4);
    int*          histA  = (int*)   alloc((size_t)G * 256 * 4);
    int*          coarse = (int*)   alloc(257 * 4);
    float*        hW     = (float*) alloc((size_t)n * HF * 4);
    float*        hA     = (float*) alloc((size_t)n * HF * 4);
    float*        hB     = (float*) alloc((size_t)n * HF * 4);
    float*        z2     = (float*) alloc((size_t)n * 4);

    const int TB = 256;
    int gbN = (n + TB - 1) / TB;
    int gbW = (n * 64 + TB - 1) / TB;
    int gbG = (n + GM_BN - 1) / GM_BN;

    // ---- CSR build (atomic-free, LDS atomics only) ----
    pA_hist   <<<G,  TB, 0, stream>>>(dst, histA, E);
    pScan     <<<1,  ST, 0, stream>>>(histA, coarse, G, E);
    pB_scatter<<<G,  TB, 0, stream>>>(src, dst, histA, tmp, E);
    pC_build  <<<NB, TB, 0, stream>>>(tmp, coarse, csrs, offs, di, dp, n, E, NB);

    // ---- layer 1 ----
    k_gemm<<<gbG, TB, 0, stream>>>(x, W_in, hW, n);
    k_agg<<<gbW, TB, 0, stream>>>(hW, offs, csrs, di, b_in, hA, n, 1, 2.0f);
    // ---- layer 2 ----
    k_gemm<<<gbG, TB, 0, stream>>>(hA, W_h1, hW, n);
    k_agg<<<gbW, TB, 0, stream>>>(hW, offs, csrs, di, b_h1, hB, n, 1, 2.0f);
    // ---- layer 3 ----
    k_gemm<<<gbG, TB, 0, stream>>>(hB, W_h2, hW, n);
    k_agg<<<gbW, TB, 0, stream>>>(hW, offs, csrs, di, b_h2, hA, n, 1, 2.0f);
    // ---- output layer ----
    k_z<<<gbW, TB, 0, stream>>>(hA, W_out, dp, z2, n);
    k_out<<<gbN, TB, 0, stream>>>(z2, offs, csrs, dp, b_out, out, n);
}

// Round 4
// 342.890 us; speedup vs baseline: 1.6930x; 1.4433x over previous
//
#include <hip/hip_runtime.h>

// GCN forward: 3x (GCNConv improved + ReLU) + GCNConv(out, 1 feature)
// N=50000 nodes, E=1.6M edges, H=64 features. All f32.
// CSR built via atomic-free MSD counting sort (LDS atomics only).
// Histogram table stored TRANSPOSED (bucket-major) so the single-block scan
// reads linear memory (R3's pScan was 205us of stride-1KB latency).

#define HF 64
#define EPB 16384         // edges per block in passes A/B

// ---------------- pass A: coarse histogram (bucket = dst>>8) ----------------
// writes histT[bucket * G + block]
__global__ __launch_bounds__(256) void pA_hist(const int* __restrict__ dst,
                                               int* __restrict__ histT, int E, int G) {
    __shared__ int h[256];
    int g = blockIdx.x, t = threadIdx.x;
    h[t] = 0;
    __syncthreads();
    int beg = g * EPB, end = min(beg + EPB, E);
    for (int i = beg + t; i < end; i += 256) atomicAdd(&h[dst[i] >> 8], 1);
    __syncthreads();
    histT[t * G + g] = h[t];
}

// ---------------- scan: linear exclusive scan of histT (bucket-major) ----------------
// in-place: histT[b*G+g] becomes the exclusive start for (bucket b, block g).
// coarse[b] = start of bucket b; coarse[256] = E.
#define ST 1024
__global__ __launch_bounds__(ST) void pScan(int* __restrict__ hist,
                                            int* __restrict__ coarse, int G, int E) {
    __shared__ int sd[ST];
    int t = threadIdx.x;
    int M = 256 * G;
    int chunk = (M + ST - 1) / ST;
    int beg = t * chunk, end = min(beg + chunk, M);
    int s = 0;
    for (int fi = beg; fi < end; ++fi) s += hist[fi];
    sd[t] = s;
    __syncthreads();
    for (int o = 1; o < ST; o <<= 1) {
        int u = (t >= o) ? sd[t - o] : 0;
        __syncthreads();
        sd[t] += u;
        __syncthreads();
    }
    int run = sd[t] - s;   // exclusive prefix at beg
    for (int fi = beg; fi < end; ++fi) {
        int v = hist[fi];
        hist[fi] = run;
        if (fi % G == 0) coarse[fi / G] = run;
        run += v;
    }
    if (t == ST - 1) coarse[256] = E;
}

// ---------------- pass B: coarse scatter (LDS cursors, no global atomics) ----------------
__global__ __launch_bounds__(256) void pB_scatter(const int* __restrict__ src,
                                                  const int* __restrict__ dst,
                                                  const int* __restrict__ histT,
                                                  unsigned int* __restrict__ tmp,
                                                  int E, int G) {
    __shared__ int cur[256];
    int g = blockIdx.x, t = threadIdx.x;
    cur[t] = histT[t * G + g];
    __syncthreads();
    int beg = g * EPB, end = min(beg + EPB, E);
    for (int i = beg + t; i < end; i += 256) {
        int d = dst[i], s = src[i];
        int pos = atomicAdd(&cur[d >> 8], 1);
        tmp[pos] = ((unsigned int)(d & 255) << 16) | (unsigned int)(s & 0xFFFF);
    }
}

// ---------------- pass C: per-bucket fine counting sort + CSR metadata ----------------
__global__ __launch_bounds__(256) void pC_build(const unsigned int* __restrict__ tmp,
                                                const int* __restrict__ coarse,
                                                ushort* __restrict__ csrs,
                                                int* __restrict__ offs,
                                                float* __restrict__ di,
                                                float* __restrict__ dp,
                                                int n, int E, int NB) {
    __shared__ int hist[256];
    __shared__ int cur[256];
    __shared__ int scanbuf[256];
    int b = blockIdx.x, t = threadIdx.x;
    int beg = coarse[b], end = coarse[b + 1];
    hist[t] = 0;
    __syncthreads();
    for (int i = beg + t; i < end; i += 256) atomicAdd(&hist[tmp[i] >> 16], 1);
    __syncthreads();
    int v = hist[t];
    scanbuf[t] = v;
    __syncthreads();
    for (int o = 1; o < 256; o <<= 1) {
        int u = (t >= o) ? scanbuf[t - o] : 0;
        __syncthreads();
        scanbuf[t] += u;
        __syncthreads();
    }
    int excl = scanbuf[t] - v;
    cur[t] = beg + excl;
    int d = (b << 8) + t;
    if (d < n) {
        offs[d] = beg + excl;
        float df = (float)v;
        di[d] = rsqrtf(df + 2.0f);   // improved=True: self-loop weight 2
        dp[d] = rsqrtf(df + 1.0f);   // output layer: improved=False
    }
    if (b == NB - 1 && t == 0) offs[n] = E;
    __syncthreads();
    for (int i = beg + t; i < end; i += 256) {
        unsigned int e = tmp[i];
        int pos = atomicAdd(&cur[e >> 16], 1);
        csrs[pos] = (ushort)(e & 0xFFFFu);
    }
}

// ---------------- dense GEMM: C[n,64] = A[n,64] @ W[64,64] ----------------
#define GM_BN 128
__global__ __launch_bounds__(256) void k_gemm(const float* __restrict__ A,
                                              const float* __restrict__ W,
                                              float* __restrict__ C, int n) {
    __shared__ float xT[64][132];
    __shared__ float Wl[64][64];
    int tid = threadIdx.x;
    int nb = blockIdx.x * GM_BN;

    for (int r = 0; r < 4; ++r) {
        int q = tid + 256 * r;
        int row = q >> 4, c4 = (q & 15) << 2;
        *(float4*)&Wl[row][c4] = *(const float4*)&W[row * 64 + c4];
    }
    for (int r = 0; r < 8; ++r) {
        int q = tid + 256 * r;
        int nl = q >> 4, k0 = (q & 15) << 2;
        float4 v = make_float4(0.f, 0.f, 0.f, 0.f);
        if (nb + nl < n) v = *(const float4*)&A[(size_t)(nb + nl) * HF + k0];
        xT[k0 + 0][nl] = v.x; xT[k0 + 1][nl] = v.y;
        xT[k0 + 2][nl] = v.z; xT[k0 + 3][nl] = v.w;
    }
    __syncthreads();

    int tx = tid & 7;
    int ty = tid >> 3;
    int f0 = tx * 8, n0 = ty * 4;
    float acc[4][8];
#pragma unroll
    for (int i = 0; i < 4; ++i)
#pragma unroll
        for (int j = 0; j < 8; ++j) acc[i][j] = 0.f;

#pragma unroll 4
    for (int k = 0; k < 64; ++k) {
        float4 xa = *(float4*)&xT[k][n0];
        float4 wa = *(float4*)&Wl[k][f0];
        float4 wb = *(float4*)&Wl[k][f0 + 4];
        float xs[4] = {xa.x, xa.y, xa.z, xa.w};
        float wsv[8] = {wa.x, wa.y, wa.z, wa.w, wb.x, wb.y, wb.z, wb.w};
#pragma unroll
        for (int i = 0; i < 4; ++i)
#pragma unroll
            for (int j = 0; j < 8; ++j) acc[i][j] += xs[i] * wsv[j];
    }

#pragma unroll
    for (int i = 0; i < 4; ++i) {
        int nn = nb + n0 + i;
        if (nn < n) {
            *(float4*)&C[(size_t)nn * HF + f0] =
                make_float4(acc[i][0], acc[i][1], acc[i][2], acc[i][3]);
            *(float4*)&C[(size_t)nn * HF + f0 + 4] =
                make_float4(acc[i][4], acc[i][5], acc[i][6], acc[i][7]);
        }
    }
}

// ---------------- sparse aggregation: one wave per node, lane=feature ----------------
__global__ void k_agg(const float* __restrict__ P, const int* __restrict__ offs,
                      const ushort* __restrict__ csrs, const float* __restrict__ di,
                      const float* __restrict__ bias, float* __restrict__ out,
                      int n, float fill) {
    int wid = (blockIdx.x * blockDim.x + threadIdx.x) >> 6;
    int f = threadIdx.x & 63;
    if (wid >= n) return;
    int beg = offs[wid], end = offs[wid + 1];
    float dw = di[wid];
    float acc = 0.f;
    int e = beg;
    int end4 = beg + ((end - beg) & ~3);
    for (; e < end4; e += 4) {
        int s0 = csrs[e + 0], s1 = csrs[e + 1], s2 = csrs[e + 2], s3 = csrs[e + 3];
        float w0 = di[s0], w1 = di[s1], w2 = di[s2], w3 = di[s3];
        float p0 = P[(size_t)s0 * HF + f];
        float p1 = P[(size_t)s1 * HF + f];
        float p2 = P[(size_t)s2 * HF + f];
        float p3 = P[(size_t)s3 * HF + f];
        acc += w0 * p0; acc += w1 * p1; acc += w2 * p2; acc += w3 * p3;
    }
    for (; e < end; ++e) {
        int s = csrs[e];
        acc += di[s] * P[(size_t)s * HF + f];
    }
    acc *= dw;
    acc += fill * dw * dw * P[(size_t)wid * HF + f];
    acc += bias[f];
    acc = fmaxf(acc, 0.f);
    out[(size_t)wid * HF + f] = acc;
}

// ---------------- layer-3 agg fused with output projection ----------------
// h3 = relu(agg + b); z2[n] = dp[n] * (h3 . Wout)   (no 12.8MB h3 round trip)
__global__ void k_agg_final(const float* __restrict__ P, const int* __restrict__ offs,
                            const ushort* __restrict__ csrs, const float* __restrict__ di,
                            const float* __restrict__ bias, const float* __restrict__ Wout,
                            const float* __restrict__ dp, float* __restrict__ z2, int n) {
    int wid = (blockIdx.x * blockDim.x + threadIdx.x) >> 6;
    int f = threadIdx.x & 63;
    if (wid >= n) return;
    int beg = offs[wid], end = offs[wid + 1];
    float dw = di[wid];
    float acc = 0.f;
    int e = beg;
    int end4 = beg + ((end - beg) & ~3);
    for (; e < end4; e += 4) {
        int s0 = csrs[e + 0], s1 = csrs[e + 1], s2 = csrs[e + 2], s3 = csrs[e + 3];
        float w0 = di[s0], w1 = di[s1], w2 = di[s2], w3 = di[s3];
        float p0 = P[(size_t)s0 * HF + f];
        float p1 = P[(size_t)s1 * HF + f];
        float p2 = P[(size_t)s2 * HF + f];
        float p3 = P[(size_t)s3 * HF + f];
        acc += w0 * p0; acc += w1 * p1; acc += w2 * p2; acc += w3 * p3;
    }
    for (; e < end; ++e) {
        int s = csrs[e];
        acc += di[s] * P[(size_t)s * HF + f];
    }
    acc *= dw;
    acc += 2.0f * dw * dw * P[(size_t)wid * HF + f];
    acc += bias[f];
    acc = fmaxf(acc, 0.f);
    float v = acc * Wout[f];
#pragma unroll
    for (int o = 32; o > 0; o >>= 1) v += __shfl_down(v, o, 64);
    if (f == 0) z2[wid] = v * dp[wid];
}

// out[n] = dp[n] * (sum_e z2[src] + z2[n]) + b_out
__global__ void k_out(const float* __restrict__ z2, const int* __restrict__ offs,
                      const ushort* __restrict__ csrs, const float* __restrict__ dp,
                      const float* __restrict__ bout, float* __restrict__ out, int n) {
    int i = blockIdx.x * blockDim.x + threadIdx.x;
    if (i >= n) return;
    int beg = offs[i], end = offs[i + 1];
    float acc = 0.f;
    for (int e = beg; e < end; ++e) acc += z2[csrs[e]];
    out[i] = dp[i] * (acc + z2[i]) + bout[0];
}

extern "C" void kernel_launch(void* const* d_in, const int* in_sizes, int n_in,
                              void* d_out, int out_size, void* d_ws, size_t ws_size,
                              hipStream_t stream) {
    const float* x    = (const float*)d_in[0];
    const int*   ei   = (const int*)d_in[1];
    const float* W_in = (const float*)d_in[2];
    const float* b_in = (const float*)d_in[3];
    const float* W_h1 = (const float*)d_in[4];
    const float* b_h1 = (const float*)d_in[5];
    const float* W_h2 = (const float*)d_in[6];
    const float* b_h2 = (const float*)d_in[7];
    const float* W_out= (const float*)d_in[8];
    const float* b_out= (const float*)d_in[9];
    float* out = (float*)d_out;

    const int n = in_sizes[0] / HF;        // 50000 (< 65536: ushort CSR ok)
    const int E = in_sizes[1] / 2;         // 1.6M
    const int* src = ei;
    const int* dst = ei + E;

    const int G  = (E + EPB - 1) / EPB;    // blocks in passes A/B
    const int NB = (n + 255) >> 8;         // coarse buckets actually populated

    char* ws = (char*)d_ws;
    size_t o = 0;
    auto alloc = [&](size_t bytes) -> void* {
        void* p = ws + o;
        o += (bytes + 255) & ~(size_t)255;
        return p;
    };
    int*          offs   = (int*)   alloc((size_t)(n + 1) * 4);
    float*        di     = (float*) alloc((size_t)n * 4);
    float*        dp     = (float*) alloc((size_t)n * 4);
    ushort*       csrs   = (ushort*)alloc((size_t)E * 2);
    unsigned int* tmp    = (unsigned int*)alloc((size_t)E * 4);
    int*          histT  = (int*)   alloc((size_t)G * 256 * 4);
    int*          coarse = (int*)   alloc(257 * 4);
    float*        hW     = (float*) alloc((size_t)n * HF * 4);
    float*        hA     = (float*) alloc((size_t)n * HF * 4);
    float*        hB     = (float*) alloc((size_t)n * HF * 4);
    float*        z2     = (float*) alloc((size_t)n * 4);

    const int TB = 256;
    int gbN = (n + TB - 1) / TB;
    int gbW = (n * 64 + TB - 1) / TB;
    int gbG = (n + GM_BN - 1) / GM_BN;

    // ---- CSR build (atomic-free, LDS atomics only) ----
    pA_hist   <<<G,  TB, 0, stream>>>(dst, histT, E, G);
    pScan     <<<1,  ST, 0, stream>>>(histT, coarse, G, E);
    pB_scatter<<<G,  TB, 0, stream>>>(src, dst, histT, tmp, E, G);
    pC_build  <<<NB, TB, 0, stream>>>(tmp, coarse, csrs, offs, di, dp, n, E, NB);

    // ---- layer 1 ----
    k_gemm<<<gbG, TB, 0, stream>>>(x, W_in, hW, n);
    k_agg<<<gbW, TB, 0, stream>>>(hW, offs, csrs, di, b_in, hA, n, 2.0f);
    // ---- layer 2 ----
    k_gemm<<<gbG, TB, 0, stream>>>(hA, W_h1, hW, n);
    k_agg<<<gbW, TB, 0, stream>>>(hW, offs, csrs, di, b_h1, hB, n, 2.0f);
    // ---- layer 3 (agg fused with output projection) ----
    k_gemm<<<gbG, TB, 0, stream>>>(hB, W_h2, hW, n);
    k_agg_final<<<gbW, TB, 0, stream>>>(hW, offs, csrs, di, b_h2, W_out, dp, z2, n);
    // ---- output layer ----
    k_out<<<gbN, TB, 0, stream>>>(z2, offs, csrs, dp, b_out, out, n);
}